// Round 5
// baseline (681.628 us; speedup 1.0000x reference)
//
#include <hip/hip_runtime.h>

typedef _Float16 half8 __attribute__((ext_vector_type(8)));
typedef _Float16 half4 __attribute__((ext_vector_type(4)));
typedef float f32x4 __attribute__((ext_vector_type(4)));

#define DEV __device__ __forceinline__

DEV f32x4 mfma16(half8 a, half8 b, f32x4 c) {
  return __builtin_amdgcn_mfma_f32_16x16x32_f16(a, b, c, 0, 0, 0);
}

DEV void load_lds16(const void* g, void* l) {
  __builtin_amdgcn_global_load_lds((const __attribute__((address_space(1))) void*)g,
                                   (__attribute__((address_space(3))) void*)l, 16, 0, 0);
}

// ---- T5 relative position bucket (replicates f32 reference semantics) ----
DEV int t5_bucket(int delta) {
  int b = (delta > 0) ? 16 : 0;
  int rp = delta < 0 ? -delta : delta;
  if (rp < 8) return b + rp;
  float lg = logf((float)rp * 0.125f);
  int large = 8 + (int)(lg / 2.772588722239781f * 8.0f);
  if (large > 15) large = 15;
  return b + large;
}

DEV float bias_val(const float* rel, int n, int h) {
  return rel[t5_bucket(n - 2047) * 16 + h];
}

// ---- prep: casts + bias tables (round-0 exact) ----------------------------
__global__ __launch_bounds__(256) void prep_kernel(
    const float* __restrict__ q, const float* __restrict__ k, const float* __restrict__ v,
    const float* __restrict__ wq, const float* __restrict__ wk, const float* __restrict__ wv,
    const float* __restrict__ wo, const float* __restrict__ rel,
    _Float16* __restrict__ Xh, _Float16* __restrict__ W3h, _Float16* __restrict__ Woh,
    _Float16* __restrict__ BiasH, float* __restrict__ Bf) {
  unsigned u = blockIdx.x * 256u + threadIdx.x;
  if (u < 6291456u) {
    unsigned p = u / 2097152u, r = u - p * 2097152u;
    const float4* s = (const float4*)(p == 0 ? q : p == 1 ? k : v);
    float4 x = s[r];
    half4 hv = {(_Float16)x.x, (_Float16)x.y, (_Float16)x.z, (_Float16)x.w};
    *(half4*)(Xh + (size_t)p * 8388608u + (size_t)r * 4u) = hv;
  } else if (u < 7340032u) {
    unsigned t = u - 6291456u;
    const float4* s;
    _Float16* d;
    if (t < 786432u) {
      unsigned p = t / 262144u, r = t - p * 262144u;
      s = (const float4*)(p == 0 ? wq : p == 1 ? wk : wv) + r;
      d = W3h + (size_t)p * 1048576u + (size_t)r * 4u;
    } else {
      unsigned r = t - 786432u;
      s = (const float4*)wo + r;
      d = Woh + (size_t)r * 4u;
    }
    float4 x = *s;
    half4 hv = {(_Float16)x.x, (_Float16)x.y, (_Float16)x.z, (_Float16)x.w};
    *(half4*)d = hv;
  } else {
    unsigned t = u - 7340032u;  // 65536 units
    int h = (int)(t >> 12), n = (int)(t & 4095u);
    Bf[h * 4096 + n] = (n <= 4094) ? bias_val(rel, n, h) : 0.f;
    half4 hv;
#pragma unroll
    for (int j = 0; j < 4; j++) {
      float bv = (n + j <= 4094) ? bias_val(rel, n + j, h) * 1.4426950408889634f : 0.f;
      hv[j] = (_Float16)bv;
    }
    *(half4*)(BiasH + (size_t)(h * 4096 + n) * 4u) = hv;
  }
}

// ---- 128x128 f16 GEMM, C = A * B^T (round-0 exact) ------------------------
template <int MODE>
__global__ __launch_bounds__(256) void gemm128(
    const _Float16* __restrict__ A, const _Float16* __restrict__ B,
    _Float16* __restrict__ D0, _Float16* __restrict__ D1, _Float16* __restrict__ D2,
    float* __restrict__ F) {
  __shared__ _Float16 Asm[128 * 64];
  __shared__ _Float16 Bsm[128 * 64];
  const int tid = threadIdx.x;
  const int w = tid >> 6, L = tid & 63;
  const int g = L >> 4, c15 = L & 15;
  const int m0 = blockIdx.x * 128, n0 = blockIdx.y * 128;
  const int z = blockIdx.z;
  const _Float16* Ab = A + ((size_t)z * 8192 + m0) * 1024;
  const _Float16* Bb = B + ((size_t)z * 1024 + n0) * 1024;
  f32x4 acc[4][4] = {};
  const int mw = (w & 1) * 64, nw = (w >> 1) * 64;
  const int wbase = tid & ~63;
  for (int k0 = 0; k0 < 1024; k0 += 64) {
    __syncthreads();
#pragma unroll
    for (int c = 0; c < 4; c++) {
      int i = c * 256 + tid;
      int row = i >> 3, pc = i & 7;
      int lc = pc ^ ((row >> 1) & 7);
      load_lds16(Ab + (size_t)row * 1024 + k0 + lc * 8, Asm + (c * 256 + wbase) * 8);
      load_lds16(Bb + (size_t)row * 1024 + k0 + lc * 8, Bsm + (c * 256 + wbase) * 8);
    }
    __builtin_amdgcn_s_waitcnt(0);
    __syncthreads();
#pragma unroll
    for (int kc = 0; kc < 2; kc++) {
      half8 af[4], bf[4];
#pragma unroll
      for (int t = 0; t < 4; t++) {
        int rowA = mw + t * 16 + c15;
        int pcA = (kc * 4 + g) ^ ((rowA >> 1) & 7);
        af[t] = *(const half8*)(Asm + rowA * 64 + pcA * 8);
        int rowB = nw + t * 16 + c15;
        int pcB = (kc * 4 + g) ^ ((rowB >> 1) & 7);
        bf[t] = *(const half8*)(Bsm + rowB * 64 + pcB * 8);
      }
#pragma unroll
      for (int mt = 0; mt < 4; mt++)
#pragma unroll
        for (int nt = 0; nt < 4; nt++)
          acc[mt][nt] = mfma16(bf[nt], af[mt], acc[mt][nt]);
    }
  }
  if (MODE == 0) {
    float scale = (z == 0) ? 0.18033688011112042f : 1.0f;  // log2(e)/8 for Q
    _Float16* dst = (z == 0) ? D0 : (z == 1) ? D1 : D2;
#pragma unroll
    for (int mt = 0; mt < 4; mt++) {
      int m = m0 + mw + mt * 16 + c15;      // row index [b][t]
      int bb = m >> 11, t = m & 2047;
#pragma unroll
      for (int nt = 0; nt < 4; nt++) {
        int n = n0 + nw + nt * 16 + g * 4;  // col index h*64+dh, 4 contiguous
        half4 hv;
#pragma unroll
        for (int r = 0; r < 4; r++) hv[r] = (_Float16)(acc[mt][nt][r] * scale);
        *(half4*)(dst + (((size_t)bb * 16 + (n >> 6)) * 2048 + t) * 64 + (n & 63)) = hv;
      }
    }
  } else {
#pragma unroll
    for (int mt = 0; mt < 4; mt++) {
      int m = m0 + mw + mt * 16 + c15;
#pragma unroll
      for (int nt = 0; nt < 4; nt++) {
        int n = n0 + nw + nt * 16 + g * 4;
        float4 fv = make_float4(acc[mt][nt][0], acc[mt][nt][1], acc[mt][nt][2], acc[mt][nt][3]);
        *(float4*)(F + (size_t)m * 1024 + n) = fv;
      }
    }
  }
}

// ---- V -> V^T per (b,h): [2048][64] -> [64][2048] (round-2 version) -------
__global__ __launch_bounds__(256) void transpose_v(const _Float16* __restrict__ V,
                                                   _Float16* __restrict__ Vt) {
  int bh = blockIdx.z * 16 + blockIdx.y;
  const _Float16* Vb = V + (size_t)bh * 2048 * 64;
  _Float16* Vtb = Vt + (size_t)bh * 64 * 2048;
  int tid = threadIdx.x;
  __shared__ _Float16 tileS[64][64];
  int t0 = blockIdx.x * 64;
#pragma unroll
  for (int c = 0; c < 2; c++) {
    int i = c * 256 + tid;
    int row = i >> 3, col = (i & 7) * 8;
    half8 vv = *(const half8*)(Vb + (size_t)(t0 + row) * 64 + col);
    int xr = 8 * ((col >> 3) & 7);
#pragma unroll
    for (int j = 0; j < 8; j++) tileS[col + j][row ^ xr] = vv[j];
  }
  __syncthreads();
  int d = tid >> 2, c = (tid & 3) * 16;
  int xr = 8 * ((d >> 3) & 7);
  half8 o0 = *(const half8*)(&tileS[d][c ^ xr]);
  half8 o1 = *(const half8*)(&tileS[d][(c + 8) ^ xr]);
  *(half8*)(Vtb + (size_t)d * 2048 + t0 + c) = o0;
  *(half8*)(Vtb + (size_t)d * 2048 + t0 + c + 8) = o1;
}

// ---- flash attention v9: k-split x2 + 3 blocks/CU occupancy ---------------
// Invariant of the old decomposition: 1 wave per 64 q-rows -> 2048 waves =
// 2 waves/SIMD chip-wide; latency-bound at ~20-25% of the pipe floor.
// v9 doubles parallel work by splitting kt into two halves (no running max
// in this softmax -> partials merge by pure addition), and fits 3 blocks/CU:
//   LDS 52 KB  (bias table -> prefetched global half4 loads, same values;
//               ones-row dropped -> lsum in f32, validated R2/R3)
//   VGPR <=168 (launch_bounds(256,3))
// Partial O (f32) + l per half; combine_k merges and normalizes.
__global__ __launch_bounds__(256, 3) void flash_attn(
    const _Float16* __restrict__ Q, const _Float16* __restrict__ K,
    const _Float16* __restrict__ Vt, const _Float16* __restrict__ BiasH,
    float* __restrict__ Op, float* __restrict__ Lp) {
  __shared__ _Float16 Kst[2][64 * 64];   // 16 KB
  __shared__ _Float16 Vst[2][64 * 64];   // 16 KB
  __shared__ _Float16 pS[4][64][40];     // 20 KB (80 B rows: 2-way-free b128)
  const int b = blockIdx.z >> 1, kh = blockIdx.z & 1;
  const int h = blockIdx.x, qb = blockIdx.y * 256;
  const int bh = b * 16 + h;
  const _Float16* Qb = Q + (size_t)bh * 2048 * 64;
  const _Float16* Kb = K + (size_t)bh * 2048 * 64;
  const _Float16* Vtb = Vt + (size_t)bh * 64 * 2048;
  const int tid = threadIdx.x, w = tid >> 6, L = tid & 63;
  const int g = L >> 4, c15 = L & 15;
  const int wbase = tid & ~63;
  const int idx0 = 1792 - qb;
  // lane-constant bias base: entry = E0 + kt*64 + p*32 + (nt2-r2)*16
  const _Float16* Bp =
      BiasH + (size_t)(h * 4096 + idx0 + 255 + g * 4 - w * 64 - c15) * 4;

  auto stage = [&](int buf, int kk) {
#pragma unroll
    for (int c = 0; c < 2; c++) {
      int i = c * 256 + tid;
      int row = i >> 3, pc = i & 7, lc = pc ^ ((row >> 1) & 7);
      load_lds16(Kb + (size_t)(kk + row) * 64 + lc * 8, &Kst[buf][(c * 256 + wbase) * 8]);
    }
#pragma unroll
    for (int c = 0; c < 2; c++) {
      int i = c * 256 + tid;
      int row = i >> 3, pc = i & 7, lc = pc ^ ((row >> 1) & 7);
      load_lds16(Vtb + (size_t)row * 2048 + kk + lc * 8, &Vst[buf][(c * 256 + wbase) * 8]);
    }
  };

  stage(0, kh * 1024);
  half8 qf[4][2];  // Q pre-scaled by log2(e)/8
#pragma unroll
  for (int r2 = 0; r2 < 4; r2++)
#pragma unroll
    for (int kc = 0; kc < 2; kc++)
      qf[r2][kc] =
          *(const half8*)(Qb + (size_t)(qb + w * 64 + r2 * 16 + c15) * 64 + kc * 32 + g * 8);
  f32x4 O[4][4] = {};
  float lsum[4] = {0.f, 0.f, 0.f, 0.f};
  __builtin_amdgcn_s_waitcnt(0);
  __syncthreads();

  for (int kt2 = 0; kt2 < 16; kt2++) {
    const int akt = kh * 16 + kt2;
    const int cur = kt2 & 1, nxt = cur ^ 1;
    if (kt2 < 15) stage(nxt, (akt + 1) * 64);  // async into other buffer
#pragma unroll
    for (int p = 0; p < 2; p++) {
      // bias prefetch for this pass (global, L2-hot; same entries as before)
      half4 bvv[4][2];
#pragma unroll
      for (int r2 = 0; r2 < 4; r2++)
#pragma unroll
        for (int nt2 = 0; nt2 < 2; nt2++)
          bvv[r2][nt2] =
              *(const half4*)(Bp + (ptrdiff_t)(akt * 64 + p * 32 + (nt2 - r2) * 16) * 4);
      // this pass's K frags (k-half p): nt = 2p, 2p+1
      half8 kf[2][2];
#pragma unroll
      for (int nt2 = 0; nt2 < 2; nt2++)
#pragma unroll
        for (int kc = 0; kc < 2; kc++) {
          int row = (2 * p + nt2) * 16 + c15;
          int pc = (kc * 4 + g) ^ ((row >> 1) & 7);
          kf[nt2][kc] = *(const half8*)(&Kst[cur][row * 64 + pc * 8]);
        }
      // S slice per r2: mfma -> bias -> exp2 -> pS (frees S immediately)
#pragma unroll
      for (int r2 = 0; r2 < 4; r2++) {
#pragma unroll
        for (int nt2 = 0; nt2 < 2; nt2++) {
          f32x4 z = {};
          f32x4 s0 = mfma16(kf[nt2][0], qf[r2][0], z);
          f32x4 S = mfma16(kf[nt2][1], qf[r2][1], s0);
          half4 bv = bvv[r2][nt2];
          half4 pv;
          float e0 = __builtin_amdgcn_exp2f(S[0] + (float)bv[0]);
          float e1 = __builtin_amdgcn_exp2f(S[1] + (float)bv[1]);
          float e2 = __builtin_amdgcn_exp2f(S[2] + (float)bv[2]);
          float e3 = __builtin_amdgcn_exp2f(S[3] + (float)bv[3]);
          lsum[r2] += (e0 + e1) + (e2 + e3);
          pv[0] = (_Float16)e0;
          pv[1] = (_Float16)e1;
          pv[2] = (_Float16)e2;
          pv[3] = (_Float16)e3;
          *(half4*)(&pS[w][r2 * 16 + c15][nt2 * 16 + g * 4]) = pv;
        }
      }
      // this pass's V frags (k-chunk p of the staged 64)
      half8 vf[4];
#pragma unroll
      for (int dt = 0; dt < 4; dt++) {
        int row = dt * 16 + c15;
        int pc = (p * 4 + g) ^ ((row >> 1) & 7);
        vf[dt] = *(const half8*)(&Vst[cur][row * 64 + pc * 8]);
      }
      __builtin_amdgcn_s_waitcnt(0xc07f);  // lgkmcnt(0): pS pass drained
      half8 pa[4];
#pragma unroll
      for (int r2 = 0; r2 < 4; r2++) pa[r2] = *(const half8*)(&pS[w][r2 * 16 + c15][g * 8]);
      __builtin_amdgcn_s_setprio(1);
#pragma unroll
      for (int r2 = 0; r2 < 4; r2++)
#pragma unroll
        for (int dt = 0; dt < 4; dt++) O[r2][dt] = mfma16(vf[dt], pa[r2], O[r2][dt]);
      __builtin_amdgcn_s_setprio(0);
    }
    __builtin_amdgcn_s_waitcnt(0);  // staging for nxt complete
    __syncthreads();                // everyone done reading cur
  }
  // epilogue: partial l (f32, g-lane reduce) + partial O (f32) to workspace
  float* Opb = Op + ((size_t)(kh * 64 + bh) * 2048) * 64;
#pragma unroll
  for (int r2 = 0; r2 < 4; r2++) {
    float ls = lsum[r2];
    ls += __shfl_xor(ls, 16, 64);
    ls += __shfl_xor(ls, 32, 64);
    int qg = qb + w * 64 + r2 * 16 + c15;
    if (g == 0) Lp[(size_t)(kh * 64 + bh) * 2048 + qg] = ls;
#pragma unroll
    for (int dt = 0; dt < 4; dt++) {
      float4 fv = make_float4(O[r2][dt][0], O[r2][dt][1], O[r2][dt][2], O[r2][dt][3]);
      *(float4*)(Opb + (size_t)qg * 64 + dt * 16 + g * 4) = fv;
    }
  }
}

// ---- combine: AO = (O_a + O_b) / (l_a + l_b), f32 -> f16 ------------------
__global__ __launch_bounds__(256) void combine_k(const float* __restrict__ Op,
                                                 const float* __restrict__ Lp,
                                                 _Float16* __restrict__ AO) {
  unsigned u = blockIdx.x * 256u + threadIdx.x;  // [bh(64)][q(2048)][d4(16)]
  int d4 = (int)(u & 15u);
  unsigned bq = u >> 4;  // bh*2048 + q
  int bh = (int)(bq >> 11), qq = (int)(bq & 2047u);
  const float4* A = (const float4*)Op + (size_t)bq * 16 + d4;
  const float4* B = A + 2097152u;  // half-stride = 64*2048*64 f32 = 2^21 float4
  float linv = 1.0f / (Lp[bq] + Lp[131072u + bq]);
  float4 a = *A, c = *B;
  half4 o;
  o[0] = (_Float16)((a.x + c.x) * linv);
  o[1] = (_Float16)((a.y + c.y) * linv);
  o[2] = (_Float16)((a.z + c.z) * linv);
  o[3] = (_Float16)((a.w + c.w) * linv);
  int b_ = bh >> 4, h = bh & 15;
  *(half4*)(AO + ((size_t)(b_ * 2048 + qq)) * 1024 + h * 64 + d4 * 4) = o;
}

// ---- position_bias output: [16][2048][2048] fp32 stream write -------------
__global__ __launch_bounds__(256) void bias_out_k(const float* __restrict__ Bf,
                                                  float4* __restrict__ out2) {
  unsigned u = blockIdx.x * 256u + threadIdx.x;
  int hh = (int)(u >> 20);
  unsigned rem = u & 1048575u;
  int i = (int)(rem >> 9);
  int j4 = (int)(rem & 511u) * 4;
  const float* p = Bf + hh * 4096 + j4 - i + 2047;
  out2[u] = make_float4(p[0], p[1], p[2], p[3]);
}

extern "C" void kernel_launch(void* const* d_in, const int* in_sizes, int n_in,
                              void* d_out, int out_size, void* d_ws, size_t ws_size,
                              hipStream_t stream) {
  const float* q = (const float*)d_in[0];
  const float* k = (const float*)d_in[1];
  const float* v = (const float*)d_in[2];
  const float* wq = (const float*)d_in[3];
  const float* wk = (const float*)d_in[4];
  const float* wv = (const float*)d_in[5];
  const float* wo = (const float*)d_in[6];
  const float* rel = (const float*)d_in[7];

  _Float16* Xh = (_Float16*)d_ws;            // [3][8192][1024]
  _Float16* W3h = Xh + 3u * 8388608u;        // [3][1024][1024]
  _Float16* Woh = W3h + 3u * 1048576u;       // [1024][1024]
  _Float16* Qh = Woh + 1048576u;             // [4][16][2048][64]
  _Float16* Kh = Qh + 8388608u;
  _Float16* Vh = Kh + 8388608u;              // [4][16][2048][64]
  _Float16* Vth = Vh + 8388608u;             // [4][16][64][2048]
  _Float16* AOh = Vth + 8388608u;            // [8192][1024]
  _Float16* BiasH = AOh + 8388608u;          // [16][4096] half4 (512 KB)
  float* Bf = (float*)(BiasH + 262144u);     // [16][4096] f32 exact (256 KB)
  float* Opart = Bf + 262144u;               // [2][64][2048][64] f32 (64 MB)
  float* Lpart = Opart + 16777216u;          // [2][64][2048] f32 (1 MB)
  float* outp = (float*)d_out;

  prep_kernel<<<28928, 256, 0, stream>>>(q, k, v, wq, wk, wv, wo, rel, Xh, W3h, Woh, BiasH, Bf);
  gemm128<0><<<dim3(64, 8, 3), 256, 0, stream>>>(Xh, W3h, Qh, Kh, Vh, nullptr);
  transpose_v<<<dim3(32, 16, 4), 256, 0, stream>>>(Vh, Vth);
  flash_attn<<<dim3(16, 8, 8), 256, 0, stream>>>(Qh, Kh, Vth, BiasH, Opart, Lpart);
  combine_k<<<8192, 256, 0, stream>>>(Opart, Lpart, AOh);
  gemm128<1><<<dim3(64, 8, 1), 256, 0, stream>>>(AOh, Woh, nullptr, nullptr, nullptr, outp);
  bias_out_k<<<65536, 256, 0, stream>>>(Bf, (float4*)(outp + 8388608u));
}

// Round 7
// 531.708 us; speedup vs baseline: 1.2820x; 1.2820x over previous
//
#include <hip/hip_runtime.h>

typedef _Float16 half8 __attribute__((ext_vector_type(8)));
typedef _Float16 half4 __attribute__((ext_vector_type(4)));
typedef float f32x4 __attribute__((ext_vector_type(4)));

#define DEV __device__ __forceinline__

DEV f32x4 mfma16(half8 a, half8 b, f32x4 c) {
  return __builtin_amdgcn_mfma_f32_16x16x32_f16(a, b, c, 0, 0, 0);
}

DEV void load_lds16(const void* g, void* l) {
  __builtin_amdgcn_global_load_lds((const __attribute__((address_space(1))) void*)g,
                                   (__attribute__((address_space(3))) void*)l, 16, 0, 0);
}

// ---- T5 relative position bucket (replicates f32 reference semantics) ----
DEV int t5_bucket(int delta) {
  int b = (delta > 0) ? 16 : 0;
  int rp = delta < 0 ? -delta : delta;
  if (rp < 8) return b + rp;
  float lg = logf((float)rp * 0.125f);
  int large = 8 + (int)(lg / 2.772588722239781f * 8.0f);
  if (large > 15) large = 15;
  return b + large;
}

DEV float bias_val(const float* rel, int n, int h) {
  return rel[t5_bucket(n - 2047) * 16 + h];
}

// ---- prep: casts + bias tables (round-0 exact) ----------------------------
__global__ __launch_bounds__(256) void prep_kernel(
    const float* __restrict__ q, const float* __restrict__ k, const float* __restrict__ v,
    const float* __restrict__ wq, const float* __restrict__ wk, const float* __restrict__ wv,
    const float* __restrict__ wo, const float* __restrict__ rel,
    _Float16* __restrict__ Xh, _Float16* __restrict__ W3h, _Float16* __restrict__ Woh,
    _Float16* __restrict__ BiasH, float* __restrict__ Bf) {
  unsigned u = blockIdx.x * 256u + threadIdx.x;
  if (u < 6291456u) {
    unsigned p = u / 2097152u, r = u - p * 2097152u;
    const float4* s = (const float4*)(p == 0 ? q : p == 1 ? k : v);
    float4 x = s[r];
    half4 hv = {(_Float16)x.x, (_Float16)x.y, (_Float16)x.z, (_Float16)x.w};
    *(half4*)(Xh + (size_t)p * 8388608u + (size_t)r * 4u) = hv;
  } else if (u < 7340032u) {
    unsigned t = u - 6291456u;
    const float4* s;
    _Float16* d;
    if (t < 786432u) {
      unsigned p = t / 262144u, r = t - p * 262144u;
      s = (const float4*)(p == 0 ? wq : p == 1 ? wk : wv) + r;
      d = W3h + (size_t)p * 1048576u + (size_t)r * 4u;
    } else {
      unsigned r = t - 786432u;
      s = (const float4*)wo + r;
      d = Woh + (size_t)r * 4u;
    }
    float4 x = *s;
    half4 hv = {(_Float16)x.x, (_Float16)x.y, (_Float16)x.z, (_Float16)x.w};
    *(half4*)d = hv;
  } else {
    unsigned t = u - 7340032u;  // 65536 units
    int h = (int)(t >> 12), n = (int)(t & 4095u);
    Bf[h * 4096 + n] = (n <= 4094) ? bias_val(rel, n, h) : 0.f;
    half4 hv;
#pragma unroll
    for (int j = 0; j < 4; j++) {
      float bv = (n + j <= 4094) ? bias_val(rel, n + j, h) * 1.4426950408889634f : 0.f;
      hv[j] = (_Float16)bv;
    }
    *(half4*)(BiasH + (size_t)(h * 4096 + n) * 4u) = hv;
  }
}

// ---- 128x128 f16 GEMM, C = A * B^T (round-0 exact) ------------------------
template <int MODE>
__global__ __launch_bounds__(256) void gemm128(
    const _Float16* __restrict__ A, const _Float16* __restrict__ B,
    _Float16* __restrict__ D0, _Float16* __restrict__ D1, _Float16* __restrict__ D2,
    float* __restrict__ F) {
  __shared__ _Float16 Asm[128 * 64];
  __shared__ _Float16 Bsm[128 * 64];
  const int tid = threadIdx.x;
  const int w = tid >> 6, L = tid & 63;
  const int g = L >> 4, c15 = L & 15;
  const int m0 = blockIdx.x * 128, n0 = blockIdx.y * 128;
  const int z = blockIdx.z;
  const _Float16* Ab = A + ((size_t)z * 8192 + m0) * 1024;
  const _Float16* Bb = B + ((size_t)z * 1024 + n0) * 1024;
  f32x4 acc[4][4] = {};
  const int mw = (w & 1) * 64, nw = (w >> 1) * 64;
  const int wbase = tid & ~63;
  for (int k0 = 0; k0 < 1024; k0 += 64) {
    __syncthreads();
#pragma unroll
    for (int c = 0; c < 4; c++) {
      int i = c * 256 + tid;
      int row = i >> 3, pc = i & 7;
      int lc = pc ^ ((row >> 1) & 7);
      load_lds16(Ab + (size_t)row * 1024 + k0 + lc * 8, Asm + (c * 256 + wbase) * 8);
      load_lds16(Bb + (size_t)row * 1024 + k0 + lc * 8, Bsm + (c * 256 + wbase) * 8);
    }
    __builtin_amdgcn_s_waitcnt(0);
    __syncthreads();
#pragma unroll
    for (int kc = 0; kc < 2; kc++) {
      half8 af[4], bf[4];
#pragma unroll
      for (int t = 0; t < 4; t++) {
        int rowA = mw + t * 16 + c15;
        int pcA = (kc * 4 + g) ^ ((rowA >> 1) & 7);
        af[t] = *(const half8*)(Asm + rowA * 64 + pcA * 8);
        int rowB = nw + t * 16 + c15;
        int pcB = (kc * 4 + g) ^ ((rowB >> 1) & 7);
        bf[t] = *(const half8*)(Bsm + rowB * 64 + pcB * 8);
      }
#pragma unroll
      for (int mt = 0; mt < 4; mt++)
#pragma unroll
        for (int nt = 0; nt < 4; nt++)
          acc[mt][nt] = mfma16(bf[nt], af[mt], acc[mt][nt]);
    }
  }
  if (MODE == 0) {
    float scale = (z == 0) ? 0.18033688011112042f : 1.0f;  // log2(e)/8 for Q
    _Float16* dst = (z == 0) ? D0 : (z == 1) ? D1 : D2;
#pragma unroll
    for (int mt = 0; mt < 4; mt++) {
      int m = m0 + mw + mt * 16 + c15;      // row index [b][t]
      int bb = m >> 11, t = m & 2047;
#pragma unroll
      for (int nt = 0; nt < 4; nt++) {
        int n = n0 + nw + nt * 16 + g * 4;  // col index h*64+dh, 4 contiguous
        half4 hv;
#pragma unroll
        for (int r = 0; r < 4; r++) hv[r] = (_Float16)(acc[mt][nt][r] * scale);
        *(half4*)(dst + (((size_t)bb * 16 + (n >> 6)) * 2048 + t) * 64 + (n & 63)) = hv;
      }
    }
  } else {
#pragma unroll
    for (int mt = 0; mt < 4; mt++) {
      int m = m0 + mw + mt * 16 + c15;
#pragma unroll
      for (int nt = 0; nt < 4; nt++) {
        int n = n0 + nw + nt * 16 + g * 4;
        float4 fv = make_float4(acc[mt][nt][0], acc[mt][nt][1], acc[mt][nt][2], acc[mt][nt][3]);
        *(float4*)(F + (size_t)m * 1024 + n) = fv;
      }
    }
  }
}

// ---- V -> V^T per (b,h): [2048][64] -> [80][2048]; row 64 = ones ----------
__global__ __launch_bounds__(256) void transpose_v(const _Float16* __restrict__ V,
                                                   _Float16* __restrict__ Vt) {
  int bh = blockIdx.z * 16 + blockIdx.y;
  const _Float16* Vb = V + (size_t)bh * 2048 * 64;
  _Float16* Vtb = Vt + (size_t)bh * 80 * 2048;
  int tid = threadIdx.x;
  if (blockIdx.x == 32) {
    _Float16 one = (_Float16)1.0f, zero = (_Float16)0.0f;
#pragma unroll
    for (int j = 0; j < 16; j++) {
      half8 vv;
#pragma unroll
      for (int e = 0; e < 8; e++) vv[e] = (j == 0) ? one : zero;
      *(half8*)(Vtb + (size_t)(64 + j) * 2048 + tid * 8) = vv;
    }
    return;
  }
  __shared__ _Float16 tileS[64][64];
  int t0 = blockIdx.x * 64;
#pragma unroll
  for (int c = 0; c < 2; c++) {
    int i = c * 256 + tid;
    int row = i >> 3, col = (i & 7) * 8;
    half8 vv = *(const half8*)(Vb + (size_t)(t0 + row) * 64 + col);
    int xr = 8 * ((col >> 3) & 7);
#pragma unroll
    for (int j = 0; j < 8; j++) tileS[col + j][row ^ xr] = vv[j];
  }
  __syncthreads();
  int d = tid >> 2, c = (tid & 3) * 16;
  int xr = 8 * ((d >> 3) & 7);
  half8 o0 = *(const half8*)(&tileS[d][c ^ xr]);
  half8 o1 = *(const half8*)(&tileS[d][(c + 8) ^ xr]);
  *(half8*)(Vtb + (size_t)d * 2048 + t0 + c) = o0;
  *(half8*)(Vtb + (size_t)d * 2048 + t0 + c + 8) = o1;
}

// ---- flash attention v10: round-0 compute, byte-identical output, plus
// fused position_bias stream-out. Flash is latency-bound with an idle HBM
// write pipe; bias_out's 268 MB write rides along: each of the 512 blocks
// owns a 512 KB slice; per kt it loads 16 f32 from L2-resident Bf at the
// iteration top and fires 4 nontemporal float4 stores after PV.
// The per-kt drain becomes a COUNTED s_waitcnt vmcnt(4) (stores are the 4
// newest vmem ops; vmcnt retires in issue order, so <=4 outstanding ==
// staging loads landed) so stores ride across barriers instead of being
// drained 32 times. Eliminates the separate bias_out_k dispatch (~45 us).
__global__ __launch_bounds__(256, 2) void flash_attn(
    const _Float16* __restrict__ Q, const _Float16* __restrict__ K,
    const _Float16* __restrict__ Vt, const _Float16* __restrict__ BiasH,
    _Float16* __restrict__ AO, const float* __restrict__ Bf,
    f32x4* __restrict__ out2) {
  __shared__ _Float16 Kst[2][64 * 64];   // 16 KB
  __shared__ _Float16 Vst[2][80 * 64];   // 20 KB
  __shared__ half4 biasS[2304];          // 18 KB
  __shared__ _Float16 pS[4][64][40];     // 20 KB (80 B rows: 2-way-free b128)
  const int b = blockIdx.z, h = blockIdx.x, qb = blockIdx.y * 256;
  const int bh = b * 16 + h;
  const _Float16* Qb = Q + (size_t)bh * 2048 * 64;
  const _Float16* Kb = K + (size_t)bh * 2048 * 64;
  const _Float16* Vtb = Vt + (size_t)bh * 80 * 2048;
  const int tid = threadIdx.x, w = tid >> 6, L = tid & 63;
  const int g = L >> 4, c15 = L & 15;
  const int wbase = tid & ~63;
  const int idx0 = 1792 - qb;
  // fused-bias slice: 512 blocks x 32768 float4 = 16M float4 total
  const unsigned u0 =
      ((unsigned)(blockIdx.z * 8 + blockIdx.y) * 16 + blockIdx.x) * 32768u + tid;

  auto stage = [&](int buf, int kk) {
#pragma unroll
    for (int c = 0; c < 2; c++) {
      int i = c * 256 + tid;
      int row = i >> 3, pc = i & 7, lc = pc ^ ((row >> 1) & 7);
      load_lds16(Kb + (size_t)(kk + row) * 64 + lc * 8, &Kst[buf][(c * 256 + wbase) * 8]);
    }
#pragma unroll
    for (int c = 0; c < 2; c++) {
      int i = c * 256 + tid;
      int row = i >> 3, pc = i & 7, lc = pc ^ ((row >> 1) & 7);
      load_lds16(Vtb + (size_t)row * 2048 + kk + lc * 8, &Vst[buf][(c * 256 + wbase) * 8]);
    }
    if (tid < 128) {
      int i = 512 + tid;
      int row = i >> 3, pc = i & 7, lc = pc ^ ((row >> 1) & 7);
      load_lds16(Vtb + (size_t)row * 2048 + kk + lc * 8, &Vst[buf][(512 + wbase) * 8]);
    }
  };

  stage(0, 0);
  for (int i = tid; i < 2304; i += 256)
    biasS[i] = *(const half4*)(BiasH + (size_t)(h * 4096 + idx0 + i) * 4u);
  half8 qf[4][2];  // Q pre-scaled by log2(e)/8
#pragma unroll
  for (int r2 = 0; r2 < 4; r2++)
#pragma unroll
    for (int kc = 0; kc < 2; kc++)
      qf[r2][kc] =
          *(const half8*)(Qb + (size_t)(qb + w * 64 + r2 * 16 + c15) * 64 + kc * 32 + g * 8);
  f32x4 O[4][5] = {};  // dt=4 = "ones" tile -> row d=64 accumulates l
  __builtin_amdgcn_s_waitcnt(0);
  __syncthreads();

  for (int kt = 0; kt < 32; kt++) {
    const int cur = kt & 1, nxt = cur ^ 1;
    // fused bias: issue the 16 Bf loads FIRST (oldest vmem of this iter)
    float bo[4][4];
    unsigned uu[4];
#pragma unroll
    for (int j = 0; j < 4; j++) {
      unsigned u = u0 + (unsigned)(kt * 4 + j) * 256u;
      uu[j] = u;
      int hh = (int)(u >> 20);
      unsigned rem = u & 1048575u;
      int i = (int)(rem >> 9);
      int j4 = (int)(rem & 511u) * 4;
      const float* p = Bf + hh * 4096 + j4 - i + 2047;
#pragma unroll
      for (int e = 0; e < 4; e++) bo[j][e] = p[e];
    }
    if (kt < 31) stage(nxt, (kt + 1) * 64);  // async into other buffer
#pragma unroll
    for (int p = 0; p < 2; p++) {
      // this pass's K frags (k-half p): nt = 2p, 2p+1
      half8 kf[2][2];
#pragma unroll
      for (int nt2 = 0; nt2 < 2; nt2++)
#pragma unroll
        for (int kc = 0; kc < 2; kc++) {
          int row = (2 * p + nt2) * 16 + c15;
          int pc = (kc * 4 + g) ^ ((row >> 1) & 7);
          kf[nt2][kc] = *(const half8*)(&Kst[cur][row * 64 + pc * 8]);
        }
      // this pass's V frags (k-chunk p of the staged 64)
      half8 vf[5];
#pragma unroll
      for (int dt = 0; dt < 5; dt++) {
        int row = dt * 16 + c15;
        int pc = (p * 4 + g) ^ ((row >> 1) & 7);
        vf[dt] = *(const half8*)(&Vst[cur][row * 64 + pc * 8]);
      }
      // S slice per r2: mfma -> bias -> exp2 -> pS (frees S immediately)
#pragma unroll
      for (int r2 = 0; r2 < 4; r2++) {
        int qloc = w * 64 + r2 * 16 + c15;
#pragma unroll
        for (int nt2 = 0; nt2 < 2; nt2++) {
          f32x4 z = {};
          f32x4 s0 = mfma16(kf[nt2][0], qf[r2][0], z);
          f32x4 S = mfma16(kf[nt2][1], qf[r2][1], s0);
          half4 bv = biasS[kt * 64 + p * 32 + nt2 * 16 + g * 4 + 255 - qloc];
          half4 pv;
#pragma unroll
          for (int r = 0; r < 4; r++)
            pv[r] = (_Float16)__builtin_amdgcn_exp2f(S[r] + (float)bv[r]);
          *(half4*)(&pS[w][r2 * 16 + c15][nt2 * 16 + g * 4]) = pv;
        }
      }
      __builtin_amdgcn_s_waitcnt(0xc07f);  // lgkmcnt(0): pS pass drained
      half8 pa[4];
#pragma unroll
      for (int r2 = 0; r2 < 4; r2++) pa[r2] = *(const half8*)(&pS[w][r2 * 16 + c15][g * 8]);
      __builtin_amdgcn_s_setprio(1);
#pragma unroll
      for (int r2 = 0; r2 < 4; r2++)
#pragma unroll
        for (int dt = 0; dt < 5; dt++) O[r2][dt] = mfma16(vf[dt], pa[r2], O[r2][dt]);
      __builtin_amdgcn_s_setprio(0);
    }
    // fused bias: fire the 4 stores (loads retired under compute)
#pragma unroll
    for (int j = 0; j < 4; j++) {
      f32x4 fv = {bo[j][0], bo[j][1], bo[j][2], bo[j][3]};
      __builtin_nontemporal_store(fv, out2 + uu[j]);
    }
    // counted drain: <=4 outstanding vmem == staging landed, stores in flight
    asm volatile("s_waitcnt vmcnt(4) lgkmcnt(0)" ::: "memory");
    __builtin_amdgcn_sched_barrier(0);
    __builtin_amdgcn_s_barrier();
    __builtin_amdgcn_sched_barrier(0);
  }
  // epilogue: l = O[r2][4][0] on lanes g==0; broadcast, scale, packed stores
#pragma unroll
  for (int r2 = 0; r2 < 4; r2++) {
    float linv = 1.0f / __shfl(O[r2][4][0], c15, 64);
    int qg = qb + w * 64 + r2 * 16 + c15;
    _Float16* dst = AO + ((size_t)(b * 2048 + qg)) * 1024 + h * 64;
#pragma unroll
    for (int dt = 0; dt < 4; dt++) {
      half4 ov;
#pragma unroll
      for (int r = 0; r < 4; r++) ov[r] = (_Float16)(O[r2][dt][r] * linv);
      *(half4*)(dst + dt * 16 + g * 4) = ov;
    }
  }
}

extern "C" void kernel_launch(void* const* d_in, const int* in_sizes, int n_in,
                              void* d_out, int out_size, void* d_ws, size_t ws_size,
                              hipStream_t stream) {
  const float* q = (const float*)d_in[0];
  const float* k = (const float*)d_in[1];
  const float* v = (const float*)d_in[2];
  const float* wq = (const float*)d_in[3];
  const float* wk = (const float*)d_in[4];
  const float* wv = (const float*)d_in[5];
  const float* wo = (const float*)d_in[6];
  const float* rel = (const float*)d_in[7];

  _Float16* Xh = (_Float16*)d_ws;            // [3][8192][1024]
  _Float16* W3h = Xh + 3u * 8388608u;        // [3][1024][1024]
  _Float16* Woh = W3h + 3u * 1048576u;       // [1024][1024]
  _Float16* Qh = Woh + 1048576u;             // [4][16][2048][64]
  _Float16* Kh = Qh + 8388608u;
  _Float16* Vh = Kh + 8388608u;
  _Float16* Vth = Vh + 8388608u;             // [4][16][80][2048]
  _Float16* AOh = Vth + 10485760u;           // [8192][1024]
  _Float16* BiasH = AOh + 8388608u;          // [16][4096] half4 (512 KB)
  float* Bf = (float*)(BiasH + 262144u);     // [16][4096] f32 exact (256 KB)
  float* outp = (float*)d_out;

  prep_kernel<<<28928, 256, 0, stream>>>(q, k, v, wq, wk, wv, wo, rel, Xh, W3h, Woh, BiasH, Bf);
  gemm128<0><<<dim3(64, 8, 3), 256, 0, stream>>>(Xh, W3h, Qh, Kh, Vh, nullptr);
  transpose_v<<<dim3(33, 16, 4), 256, 0, stream>>>(Vh, Vth);
  flash_attn<<<dim3(16, 8, 4), 256, 0, stream>>>(Qh, Kh, Vth, BiasH, AOh, Bf,
                                                 (f32x4*)(outp + 8388608u));
  gemm128<1><<<dim3(64, 8, 1), 256, 0, stream>>>(AOh, Woh, nullptr, nullptr, nullptr, outp);
}